// Round 2
// baseline (834.575 us; speedup 1.0000x reference)
//
#include <hip/hip_runtime.h>
#include <cstdint>

#define S_LEN 4096
#define D_DIM 256

// workspace layout (float offsets)
#define OFF_MINP 0
#define OFF_WPT  16
#define OFF_WTH  (OFF_WPT + 768*256)     // WeffT hi, 768x768 ushort = 294912 floats
#define OFF_WTL  (OFF_WTH + 294912)      // WeffT lo
#define OFF_C    (OFF_WTL + 294912)      // == old OFF_C, downstream unchanged
#define OFF_HH   (OFF_C + 8*768*4096)
#define OFF_V    (OFF_HH + 8*2*256*4096)
#define OFF_U    (OFF_V + 8*256*4096)

// FF weight splits live at the head of the V region (vb is only written by
// k_conv_mfma #1, which runs AFTER k_ff has consumed these — stream-order safe).
// w1th: 256*256 ushort | w1tl | w2th: 512*256 | w2tl  => 786432 B total.

typedef __attribute__((ext_vector_type(8))) short short8;
typedef __attribute__((ext_vector_type(4))) float f32x4;

__device__ __forceinline__ unsigned int f2bf(float x) {
    union { float f; unsigned int u; } v; v.f = x;
    unsigned int r = v.u + 0x7fffu + ((v.u >> 16) & 1u);   // RNE
    return r >> 16;
}
__device__ __forceinline__ float bf2f(unsigned int h) {
    union { unsigned int u; float f; } v; v.u = h << 16; return v.f;
}

// ---------------- min valid position per batch ----------------
__global__ __launch_bounds__(256) void k_minpos(const int* __restrict__ pos, float* __restrict__ minp)
{
    const int b = blockIdx.x;
    const int tid = threadIdx.x;
    int mn = 0x7fffffff;
    const int* p = pos + (size_t)b * S_LEN;
    for (int s = tid; s < S_LEN; s += 256) {
        const int v = p[s];
        if (v != -1) mn = min(mn, v);
    }
    __shared__ int red[256];
    red[tid] = mn;
    __syncthreads();
    for (int st = 128; st > 0; st >>= 1) {
        if (tid < st) red[tid] = min(red[tid], red[tid + st]);
        __syncthreads();
    }
    if (tid == 0) minp[b] = (float)red[0];
}

// ---------------- transpose W_proj (256x768) -> WpT (768x256) ----------------
__global__ __launch_bounds__(256) void k_wpt(const float* __restrict__ Wp, float* __restrict__ WpT)
{
    __shared__ float t[32][33];
    const int e0 = blockIdx.x * 32;   // 0..767
    const int d0 = blockIdx.y * 32;   // 0..255
    const int lx = threadIdx.x & 31, ly = threadIdx.x >> 5; // 32x8
#pragma unroll
    for (int q = 0; q < 4; ++q)
        t[ly + 8*q][lx] = Wp[(size_t)(d0 + ly + 8*q) * 768 + e0 + lx];
    __syncthreads();
#pragma unroll
    for (int q = 0; q < 4; ++q)
        WpT[(size_t)(e0 + ly + 8*q) * 256 + d0 + lx] = t[lx][ly + 8*q];
}

// ---------------- generic transpose + bf16 hi/lo split: W[K][N] -> out[N][K] ----------------
__global__ __launch_bounds__(256) void k_tsplit(const float* __restrict__ W, const int K, const int N,
                                                unsigned short* __restrict__ oh, unsigned short* __restrict__ ol)
{
    __shared__ float t[32][33];
    const int n0 = blockIdx.x * 32;
    const int k0 = blockIdx.y * 32;
    const int lx = threadIdx.x & 31, ly = threadIdx.x >> 5;
#pragma unroll
    for (int q = 0; q < 4; ++q)
        t[ly + 8*q][lx] = W[(size_t)(k0 + ly + 8*q) * N + n0 + lx];
    __syncthreads();
#pragma unroll
    for (int q = 0; q < 4; ++q) {
        const float v = t[lx][ly + 8*q];
        const unsigned int h = f2bf(v);
        oh[(size_t)(n0 + ly + 8*q) * K + k0 + lx] = (unsigned short)h;
        ol[(size_t)(n0 + ly + 8*q) * K + k0 + lx] = (unsigned short)f2bf(v - bf2f(h));
    }
}

// ---------------- WeffT[o][t*256+d] = sum_i WpT[g*256+i][d] * conv_w[o][i][t], split hi/lo bf16 ----------------
__global__ __launch_bounds__(256) void k_weff(const float* __restrict__ WpT, const float* __restrict__ cw,
                                              unsigned short* __restrict__ wth, unsigned short* __restrict__ wtl)
{
    const int o = blockIdx.x;       // 768
    const int d = threadIdx.x;      // 256
    const int g = o >> 8;
    __shared__ float cwrow[768];
    for (int i = threadIdx.x; i < 768; i += 256) cwrow[i] = cw[(size_t)o * 768 + i];
    __syncthreads();
    float a0 = 0.f, a1 = 0.f, a2 = 0.f;
    const float* wb = WpT + (size_t)(g * 256) * 256 + d;
#pragma unroll 4
    for (int i = 0; i < 256; ++i) {
        const float wv = wb[(size_t)i * 256];
        a0 += wv * cwrow[i*3+0];
        a1 += wv * cwrow[i*3+1];
        a2 += wv * cwrow[i*3+2];
    }
    const float av[3] = {a0, a1, a2};
#pragma unroll
    for (int t = 0; t < 3; ++t) {
        const unsigned int hb = f2bf(av[t]);
        const unsigned int lb = f2bf(av[t] - bf2f(hb));
        wth[(size_t)o * 768 + t * 256 + d] = (unsigned short)hb;
        wtl[(size_t)o * 768 + t * 256 + d] = (unsigned short)lb;
    }
}

// ---------------- MFMA conv-GEMM (unchanged, verified) ----------------
#define CG_LDA 40
__global__ __launch_bounds__(256, 2) void k_convgemm(
    const float* __restrict__ emb, const int* __restrict__ pos,
    const unsigned short* __restrict__ wth, const unsigned short* __restrict__ wtl,
    const float* __restrict__ convb, float* __restrict__ c)
{
    const int b  = blockIdx.z;
    const int o0 = blockIdx.y * 128;
    const int s0 = blockIdx.x * 128;
    const int tid  = threadIdx.x;
    const int wave = tid >> 6, lane = tid & 63;
    const int m16  = lane & 15, quad = lane >> 4;

    __shared__ __align__(16) unsigned short Ah[130 * CG_LDA];
    __shared__ __align__(16) unsigned short Al[130 * CG_LDA];
    __shared__ __align__(16) unsigned short Bh[128 * CG_LDA];
    __shared__ __align__(16) unsigned short Bl[128 * CG_LDA];

    f32x4 acc[2][8];
#pragma unroll
    for (int mt = 0; mt < 2; ++mt)
#pragma unroll
        for (int nt = 0; nt < 8; ++nt)
#pragma unroll
            for (int e = 0; e < 4; ++e) acc[mt][nt][e] = 0.f;

    for (int c8 = 0; c8 < 8; ++c8) {
        for (int t = 0; t < 3; ++t) {
            if (t == 0) {
                for (int task = tid; task < 1040; task += 256) {
                    const int r = task >> 3;
                    const int g = task & 7;
                    const int srow = s0 + r - 1;
                    float4 v = make_float4(0.f, 0.f, 0.f, 0.f);
                    if (srow >= 0 && srow < S_LEN)
                        v = *(const float4*)(emb + ((size_t)b * S_LEN + srow) * D_DIM + c8 * 32 + g * 4);
                    const unsigned int hx = f2bf(v.x), hy = f2bf(v.y), hz = f2bf(v.z), hw = f2bf(v.w);
                    uint2 hp, lp;
                    hp.x = hx | (hy << 16);
                    hp.y = hz | (hw << 16);
                    lp.x = f2bf(v.x - bf2f(hx)) | (f2bf(v.y - bf2f(hy)) << 16);
                    lp.y = f2bf(v.z - bf2f(hz)) | (f2bf(v.w - bf2f(hw)) << 16);
                    *(uint2*)&Ah[r * CG_LDA + g * 4] = hp;
                    *(uint2*)&Al[r * CG_LDA + g * 4] = lp;
                }
            }
            for (int task = tid; task < 512; task += 256) {
                const int r = task >> 2;
                const int g = task & 3;
                const size_t gi = (size_t)(o0 + r) * 768 + t * 256 + c8 * 32 + g * 8;
                *(uint4*)&Bh[r * CG_LDA + g * 8] = *(const uint4*)(wth + gi);
                *(uint4*)&Bl[r * CG_LDA + g * 8] = *(const uint4*)(wtl + gi);
            }
            __syncthreads();
            short8 ah[2], al[2];
#pragma unroll
            for (int mt = 0; mt < 2; ++mt) {
                const int ar = (wave * 32 + mt * 16 + m16 + t) * CG_LDA + quad * 8;
                ah[mt] = *(const short8*)&Ah[ar];
                al[mt] = *(const short8*)&Al[ar];
            }
#pragma unroll
            for (int nt = 0; nt < 8; ++nt) {
                const int br = (nt * 16 + m16) * CG_LDA + quad * 8;
                const short8 bh = *(const short8*)&Bh[br];
                const short8 bl = *(const short8*)&Bl[br];
#pragma unroll
                for (int mt = 0; mt < 2; ++mt) {
                    acc[mt][nt] = __builtin_amdgcn_mfma_f32_16x16x32_bf16(ah[mt], bh, acc[mt][nt], 0, 0, 0);
                    acc[mt][nt] = __builtin_amdgcn_mfma_f32_16x16x32_bf16(ah[mt], bl, acc[mt][nt], 0, 0, 0);
                    acc[mt][nt] = __builtin_amdgcn_mfma_f32_16x16x32_bf16(al[mt], bh, acc[mt][nt], 0, 0, 0);
                }
            }
            __syncthreads();
        }
    }

    float msk[2][4];
#pragma unroll
    for (int mt = 0; mt < 2; ++mt) {
        const int s = s0 + wave * 32 + mt * 16 + quad * 4;
        const int4 p4 = *(const int4*)(pos + (size_t)b * S_LEN + s);
        msk[mt][0] = (p4.x != -1) ? 1.f : 0.f;
        msk[mt][1] = (p4.y != -1) ? 1.f : 0.f;
        msk[mt][2] = (p4.z != -1) ? 1.f : 0.f;
        msk[mt][3] = (p4.w != -1) ? 1.f : 0.f;
    }
#pragma unroll
    for (int nt = 0; nt < 8; ++nt) {
        const int o = o0 + nt * 16 + m16;
        const float cb = convb[o];
#pragma unroll
        for (int mt = 0; mt < 2; ++mt) {
            const int s = s0 + wave * 32 + mt * 16 + quad * 4;
            float4 r;
            r.x = (acc[mt][nt][0] + cb) * msk[mt][0];
            r.y = (acc[mt][nt][1] + cb) * msk[mt][1];
            r.z = (acc[mt][nt][2] + cb) * msk[mt][2];
            r.w = (acc[mt][nt][3] + cb) * msk[mt][3];
            *(float4*)(c + ((size_t)(b * 768 + o)) * S_LEN + s) = r;
        }
    }
}

// ---------------- NEW: RoPE + FF (MFMA) + L1-normalize -> hh[b][i][d][s] ----------------
// 64 s-rows per block, 4 waves; wave w owns rows [16w,16w+16). 3-pass bf16-split MFMA
// for both GEMMs (frag conventions == k_convgemm, verified). LN/GELU/L1-norm in-register
// with shfl_xor reductions over the 16 lanes sharing a quad (m16 group).
#define FF_LDA 264   // 256 + 8 ushort pad: rows 528B apart (33*16B, 16B-aligned frags)
__global__ __launch_bounds__(256, 2) void k_ff(
    const float* __restrict__ emb, const int* __restrict__ pos, const float* __restrict__ minp,
    const unsigned short* __restrict__ w1th, const unsigned short* __restrict__ w1tl,
    const float* __restrict__ b1,
    const float* __restrict__ lng, const float* __restrict__ lnb,
    const unsigned short* __restrict__ w2th, const unsigned short* __restrict__ w2tl,
    const float* __restrict__ b2, const float* __restrict__ ffs, float* __restrict__ hh)
{
    const int b   = blockIdx.y;
    const int s0  = blockIdx.x * 64;
    const int tid = threadIdx.x;
    const int wave = tid >> 6, lane = tid & 63;
    const int m16  = lane & 15, quad = lane >> 4;

    __shared__ __align__(16) unsigned short Th[64 * FF_LDA];
    __shared__ __align__(16) unsigned short Tl[64 * FF_LDA];
    __shared__ float th_s[128];
    __shared__ float pars[1792];   // b1[0:256) lng[256:512) lnb[512:768) b2[768:1280) ffs[1280:1792)

    // ---- stage theta table + params ----
    if (tid < 128) th_s[tid] = expf(-(float)tid * 0.07195578415606394f);
    for (int i = tid; i < 1792; i += 256) {
        float v;
        if      (i < 256)  v = b1[i];
        else if (i < 512)  v = lng[i - 256];
        else if (i < 768)  v = lnb[i - 512];
        else if (i < 1280) v = b2[i - 768];
        else               v = ffs[i - 1280];
        pars[i] = v;
    }
    __syncthreads();

    // ---- RoPE -> Th/Tl (each thread: 1/4 of one row = 64 cols = 32 pairs) ----
    {
        const int r    = tid >> 2;            // 0..63 (row of this wave's 16-row band)
        const int col0 = (tid & 3) * 64;
        const int s    = s0 + r;
        const int p    = pos[(size_t)b * S_LEN + s];
        const float adj = (p == -1) ? -1.f : ((float)p - minp[b]);
        const float* ep = emb + ((size_t)b * S_LEN + s) * D_DIM;
#pragma unroll
        for (int p8 = 0; p8 < 8; ++p8) {
            const int cbase = col0 + p8 * 8;
            const float4 va = *(const float4*)(ep + cbase);
            const float4 vb4 = *(const float4*)(ep + cbase + 4);
            const float x[8] = {va.x, va.y, va.z, va.w, vb4.x, vb4.y, vb4.z, vb4.w};
            unsigned int uh[4], ul[4];
#pragma unroll
            for (int jj = 0; jj < 4; ++jj) {
                const int j = (cbase >> 1) + jj;
                const float theta = th_s[j];
                float sn, cs;
                sincosf(adj * theta, &sn, &cs);
                const float x1 = x[2*jj], x2 = x[2*jj+1];
                const float r1 = x1 * cs - x2 * sn;
                const float r2 = x1 * sn + x2 * cs;
                const unsigned int h1 = f2bf(r1), h2 = f2bf(r2);
                uh[jj] = h1 | (h2 << 16);
                ul[jj] = f2bf(r1 - bf2f(h1)) | (f2bf(r2 - bf2f(h2)) << 16);
            }
            uint4 wh, wl;
            wh.x = uh[0]; wh.y = uh[1]; wh.z = uh[2]; wh.w = uh[3];
            wl.x = ul[0]; wl.y = ul[1]; wl.z = ul[2]; wl.w = ul[3];
            *(uint4*)&Th[r * FF_LDA + cbase] = wh;
            *(uint4*)&Tl[r * FF_LDA + cbase] = wl;
        }
    }
    __syncthreads();

    // ---- GEMM1: H[64x256] = T @ W1 (3-pass split) ----
    const int rowA = wave * 16 + m16;
    f32x4 acc1[16];
#pragma unroll
    for (int nt = 0; nt < 16; ++nt)
#pragma unroll
        for (int e = 0; e < 4; ++e) acc1[nt][e] = 0.f;

    for (int c8 = 0; c8 < 8; ++c8) {
        const int k0 = c8 * 32;
        const int ar = rowA * FF_LDA + k0 + quad * 8;
        const short8 ah = *(const short8*)&Th[ar];
        const short8 al = *(const short8*)&Tl[ar];
#pragma unroll
        for (int nt = 0; nt < 16; ++nt) {
            const size_t bi = (size_t)(nt * 16 + m16) * 256 + k0 + quad * 8;
            const short8 bh = *(const short8*)(w1th + bi);
            const short8 bl = *(const short8*)(w1tl + bi);
            acc1[nt] = __builtin_amdgcn_mfma_f32_16x16x32_bf16(ah, bh, acc1[nt], 0, 0, 0);
            acc1[nt] = __builtin_amdgcn_mfma_f32_16x16x32_bf16(ah, bl, acc1[nt], 0, 0, 0);
            acc1[nt] = __builtin_amdgcn_mfma_f32_16x16x32_bf16(al, bh, acc1[nt], 0, 0, 0);
        }
    }

    // ---- +b1, LayerNorm stats (in-register, shfl over m16 group) ----
    float sume[4] = {0.f, 0.f, 0.f, 0.f}, sumq[4] = {0.f, 0.f, 0.f, 0.f};
#pragma unroll
    for (int nt = 0; nt < 16; ++nt) {
        const float bb = pars[nt * 16 + m16];
#pragma unroll
        for (int e = 0; e < 4; ++e) {
            const float v = acc1[nt][e] + bb;
            acc1[nt][e] = v;
            sume[e] += v;
            sumq[e] += v * v;
        }
    }
#pragma unroll
    for (int e = 0; e < 4; ++e) {
#pragma unroll
        for (int off = 1; off < 16; off <<= 1) {
            sume[e] += __shfl_xor(sume[e], off, 64);
            sumq[e] += __shfl_xor(sumq[e], off, 64);
        }
    }
    float mu[4], rs[4];
#pragma unroll
    for (int e = 0; e < 4; ++e) {
        mu[e] = sume[e] * (1.f / 256.f);
        const float var = sumq[e] * (1.f / 256.f) - mu[e] * mu[e];
        rs[e] = rsqrtf(var + 1e-5f);
    }

    // ---- LN + GELU + split, write H back into Th/Tl (rows owned by this wave) ----
    __syncthreads();   // all waves done reading T from LDS
#pragma unroll
    for (int nt = 0; nt < 16; ++nt) {
        const int col = nt * 16 + m16;
        const float g  = pars[256 + col];
        const float be = pars[512 + col];
#pragma unroll
        for (int e = 0; e < 4; ++e) {
            const float h  = (acc1[nt][e] - mu[e]) * rs[e] * g + be;
            const float hg = 0.5f * h * (1.f + erff(h * 0.7071067811865475f));
            const unsigned int hb = f2bf(hg);
            const int li = (wave * 16 + quad * 4 + e) * FF_LDA + col;
            Th[li] = (unsigned short)hb;
            Tl[li] = (unsigned short)f2bf(hg - bf2f(hb));
        }
    }
    __syncthreads();

    // ---- GEMM2: A[64x512] = Hg @ W2 (3-pass split) ----
    f32x4 acc2[32];
#pragma unroll
    for (int nt = 0; nt < 32; ++nt)
#pragma unroll
        for (int e = 0; e < 4; ++e) acc2[nt][e] = 0.f;

    for (int c8 = 0; c8 < 8; ++c8) {
        const int k0 = c8 * 32;
        const int ar = rowA * FF_LDA + k0 + quad * 8;
        const short8 ah = *(const short8*)&Th[ar];
        const short8 al = *(const short8*)&Tl[ar];
#pragma unroll
        for (int nt = 0; nt < 32; ++nt) {
            const size_t bi = (size_t)(nt * 16 + m16) * 256 + k0 + quad * 8;
            const short8 bh = *(const short8*)(w2th + bi);
            const short8 bl = *(const short8*)(w2tl + bi);
            acc2[nt] = __builtin_amdgcn_mfma_f32_16x16x32_bf16(ah, bh, acc2[nt], 0, 0, 0);
            acc2[nt] = __builtin_amdgcn_mfma_f32_16x16x32_bf16(ah, bl, acc2[nt], 0, 0, 0);
            acc2[nt] = __builtin_amdgcn_mfma_f32_16x16x32_bf16(al, bh, acc2[nt], 0, 0, 0);
        }
    }

    // ---- (a+b2)*ffs, L1-norm per (row, half), store hh[b][i][d][s] ----
    float sm[2][4] = {{0.f,0.f,0.f,0.f},{0.f,0.f,0.f,0.f}};
#pragma unroll
    for (int nt = 0; nt < 32; ++nt) {
        const int col = nt * 16 + m16;
        const float bb = pars[768 + col];
        const float fs = pars[1280 + col];
#pragma unroll
        for (int e = 0; e < 4; ++e) {
            const float v = (acc2[nt][e] + bb) * fs;
            acc2[nt][e] = v;
            sm[nt >> 4][e] += fabsf(v);
        }
    }
#pragma unroll
    for (int i = 0; i < 2; ++i)
#pragma unroll
        for (int e = 0; e < 4; ++e) {
#pragma unroll
            for (int off = 1; off < 16; off <<= 1)
                sm[i][e] += __shfl_xor(sm[i][e], off, 64);
        }
#pragma unroll
    for (int nt = 0; nt < 32; ++nt) {
        const int i = nt >> 4;
        const int d = (nt & 15) * 16 + m16;
        float4 o4;
        o4.x = acc2[nt][0] / (sm[i][0] + 1e-8f);
        o4.y = acc2[nt][1] / (sm[i][1] + 1e-8f);
        o4.z = acc2[nt][2] / (sm[i][2] + 1e-8f);
        o4.w = acc2[nt][3] / (sm[i][3] + 1e-8f);
        *(float4*)(hh + ((size_t)((b * 2 + i) * 256 + d)) * S_LEN + s0 + wave * 16 + quad * 4) = o4;
    }
}

// ---------------- MFMA blocked-Toeplitz causal long conv (unchanged) ----------------
#define XS_PAD   960
#define XS_ELEMS 5056
#define FRX_WORDS 4160
__device__ __forceinline__ int xsw(int blk) { return blk ^ ((blk >> 3) & 7); }

__global__ __launch_bounds__(64) void k_conv_mfma(
    const float* __restrict__ xbuf, const int xC, const int xoff,
    const float* __restrict__ hh, const int iord,
    const float* __restrict__ cbuf, float* __restrict__ outb)
{
    const int d = blockIdx.x;
    const int b = blockIdx.y;
    const int lane = threadIdx.x;
    const float* xp = xbuf + ((size_t)(b * xC + xoff + d)) * S_LEN;
    const float* fp = hh   + ((size_t)((b * 2 + iord) * 256 + d)) * S_LEN;
    const float* zp = cbuf + ((size_t)(b * 768 + iord * 256 + d)) * S_LEN;
    float* op = outb + ((size_t)(b * 256 + d)) * S_LEN;

    __shared__ unsigned short xs[XS_ELEMS];
    __shared__ unsigned int   frx[FRX_WORDS];

    {
        for (int blk = lane; blk < 120; blk += 64) {
            int4 z; z.x = 0; z.y = 0; z.z = 0; z.w = 0;
            *(int4*)(xs + xsw(blk) * 8) = z;
        }
#pragma unroll
        for (int it = 0; it < 8; ++it) {
            const int idx = it * 64 + lane;
            const int j = idx * 8;
            const float4 v0 = *(const float4*)(xp + j);
            const float4 v1 = *(const float4*)(xp + j + 4);
            int4 w;
            w.x = (int)(f2bf(v0.x) | (f2bf(v0.y) << 16));
            w.y = (int)(f2bf(v0.z) | (f2bf(v0.w) << 16));
            w.z = (int)(f2bf(v1.x) | (f2bf(v1.y) << 16));
            w.w = (int)(f2bf(v1.z) | (f2bf(v1.w) << 16));
            *(int4*)(xs + xsw(120 + idx) * 8) = w;
        }
    }
    {
        frx[4096 + lane] = 0u;
        if (lane == 0) frx[4095] = f2bf(fp[0]);
#pragma unroll
        for (int it = 0; it < 16; ++it) {
            const int j = (it * 64 + lane) * 4;
            const float4 v = *(const float4*)(fp + j);
            const float f4 = (j + 4 < S_LEN) ? fp[j + 4] : 0.f;
            frx[4094 - j] = f2bf(v.y) | (f2bf(v.x) << 16);
            frx[4093 - j] = f2bf(v.z) | (f2bf(v.y) << 16);
            frx[4092 - j] = f2bf(v.w) | (f2bf(v.z) << 16);
            if (j < 4092) frx[4091 - j] = f2bf(f4) | (f2bf(v.w) << 16);
        }
    }
    __syncthreads();

    const int m    = lane & 15;
    const int quad = lane >> 4;

    f32x4 acc[4][4];
#pragma unroll
    for (int mt = 0; mt < 4; ++mt)
#pragma unroll
        for (int pt = 0; pt < 4; ++pt)
#pragma unroll
            for (int e = 0; e < 4; ++e) acc[mt][pt][e] = 0.f;

    const int eA_base = 4095 - m + quad * 8;
    const int oB_base = XS_PAD + 64 * m + quad * 8;

    for (int r = 0; r < 64; ++r) {
        const int ea_r = eA_base - 64 * r;
        short8 afr[4][2];
#pragma unroll
        for (int mt = 0; mt < 4; ++mt)
#pragma unroll
            for (int kc = 0; kc < 2; ++kc) {
                const int e = ea_r - 16 * mt + 32 * kc;
                union { unsigned int u[4]; short8 s; } cvt;
                cvt.u[0] = frx[e];
                cvt.u[1] = frx[e + 2];
                cvt.u[2] = frx[e + 4];
                cvt.u[3] = frx[e + 6];
                afr[mt][kc] = cvt.s;
            }
        const int ptmin = r >> 4;
        const int ob_r = oB_base - 64 * r;
#pragma unroll
        for (int pt = 0; pt < 4; ++pt) {
            if (pt >= ptmin) {
                const int o0 = ob_r + 1024 * pt;
                const short8 bfr0 = *(const short8*)(xs + xsw(o0 >> 3) * 8);
                const short8 bfr1 = *(const short8*)(xs + xsw((o0 + 32) >> 3) * 8);
#pragma unroll
                for (int mt = 0; mt < 4; ++mt) {
                    acc[mt][pt] = __builtin_amdgcn_mfma_f32_16x16x32_bf16(afr[mt][0], bfr0, acc[mt][pt], 0, 0, 0);
                    acc[mt][pt] = __builtin_amdgcn_mfma_f32_16x16x32_bf16(afr[mt][1], bfr1, acc[mt][pt], 0, 0, 0);
                }
            }
        }
    }

    const float inv = 1.f / 8192.f;
#pragma unroll
    for (int mt = 0; mt < 4; ++mt)
#pragma unroll
        for (int pt = 0; pt < 4; ++pt) {
            const int p  = 16 * pt + m;
            const int s0 = 64 * p + 16 * mt + quad * 4;
            const float4 z4 = *(const float4*)(zp + s0);
            float4 o4;
            o4.x = z4.x * acc[mt][pt][0] * inv;
            o4.y = z4.y * acc[mt][pt][1] * inv;
            o4.z = z4.z * acc[mt][pt][2] * inv;
            o4.w = z4.w * acc[mt][pt][3] * inv;
            *(float4*)(op + s0) = o4;
        }
}

// ---------------- out[b][s][e] = mask * (sum_d v[b][d][s] * W_out[d][e] + b_out[e]) ----------------
__global__ __launch_bounds__(256) void k_out(
    const float* __restrict__ v, const float* __restrict__ Wo,
    const float* __restrict__ bo, const int* __restrict__ pos,
    float* __restrict__ out)
{
    const int b   = blockIdx.y;
    const int s0  = blockIdx.x * 32;
    const int tid = threadIdx.x;
    __shared__ float vs[256 * 36];
    {
        const float4* src = (const float4*)(v + ((size_t)(b*256 + tid)) * S_LEN + s0);
#pragma unroll
        for (int q = 0; q < 8; ++q) {
            *(float4*)&vs[tid*36 + q*4] = src[q];
        }
    }
    __syncthreads();
    float acc[32];
#pragma unroll
    for (int r = 0; r < 32; ++r) acc[r] = 0.f;
    for (int dd = 0; dd < 256; ++dd) {
        const float w = Wo[(size_t)dd * 256 + tid];
        const float* vr = &vs[dd * 36];
#pragma unroll
        for (int q = 0; q < 8; ++q) {
            const float4 x4 = *(const float4*)&vr[q*4];
            acc[q*4+0] += x4.x * w;
            acc[q*4+1] += x4.y * w;
            acc[q*4+2] += x4.z * w;
            acc[q*4+3] += x4.w * w;
        }
    }
    const float bb = bo[tid];
#pragma unroll
    for (int r = 0; r < 32; ++r) {
        const int s = s0 + r;
        const float m = (pos[(size_t)b * S_LEN + s] != -1) ? 1.f : 0.f;
        out[((size_t)b * S_LEN + s) * 256 + tid] = (acc[r] + bb) * m;
    }
}

extern "C" void kernel_launch(void* const* d_in, const int* in_sizes, int n_in,
                              void* d_out, int out_size, void* d_ws, size_t ws_size,
                              hipStream_t stream) {
    const float* emb = (const float*)d_in[0];
    const int*   pos = (const int*)  d_in[1];
    const float* Wp  = (const float*)d_in[2];
    const float* cw  = (const float*)d_in[3];
    const float* cb  = (const float*)d_in[4];
    const float* W1  = (const float*)d_in[5];
    const float* b1  = (const float*)d_in[6];
    const float* lg  = (const float*)d_in[7];
    const float* lb  = (const float*)d_in[8];
    const float* W2  = (const float*)d_in[9];
    const float* b2  = (const float*)d_in[10];
    const float* ffs = (const float*)d_in[11];
    const float* Wo  = (const float*)d_in[12];
    const float* bo  = (const float*)d_in[13];

    float* ws   = (float*)d_ws;
    float* minp = ws + OFF_MINP;
    float* wpt  = ws + OFF_WPT;
    unsigned short* wth = (unsigned short*)(ws + OFF_WTH);
    unsigned short* wtl = (unsigned short*)(ws + OFF_WTL);
    float* c    = ws + OFF_C;
    float* hh   = ws + OFF_HH;
    float* vb   = ws + OFF_V;
    float* ub   = ws + OFF_U;

    // FF weight splits carved from the head of vb (consumed by k_ff before conv#1 writes vb)
    unsigned short* w1th = (unsigned short*)vb;
    unsigned short* w1tl = w1th + 256 * 256;
    unsigned short* w2th = w1tl + 256 * 256;
    unsigned short* w2tl = w2th + 512 * 256;

    k_minpos<<<dim3(8), dim3(256), 0, stream>>>(pos, minp);
    k_wpt<<<dim3(24, 8), dim3(256), 0, stream>>>(Wp, wpt);
    k_weff<<<dim3(768), dim3(256), 0, stream>>>(wpt, cw, wth, wtl);
    k_tsplit<<<dim3(8, 8), dim3(256), 0, stream>>>(W1, 256, 256, w1th, w1tl);
    k_tsplit<<<dim3(16, 8), dim3(256), 0, stream>>>(W2, 256, 512, w2th, w2tl);
    k_convgemm<<<dim3(32, 6, 8), dim3(256), 0, stream>>>(emb, pos, wth, wtl, cb, c);
    k_ff<<<dim3(64, 8), dim3(256), 0, stream>>>(emb, pos, minp, w1th, w1tl, b1, lg, lb, w2th, w2tl, b2, ffs, hh);
    // v = zs[2]; v = zs[0] * longconv(v, hh[:,0]); v = zs[1] * longconv(v, hh[:,1])
    k_conv_mfma<<<dim3(256, 8), dim3(64), 0, stream>>>(c, 768, 512, hh, 0, c, vb);
    k_conv_mfma<<<dim3(256, 8), dim3(64), 0, stream>>>(vb, 256, 0, hh, 1, c, ub);
    k_out<<<dim3(128, 8), dim3(256), 0, stream>>>(ub, Wo, bo, pos, (float*)d_out);
}

// Round 3
// 578.114 us; speedup vs baseline: 1.4436x; 1.4436x over previous
//
#include <hip/hip_runtime.h>
#include <cstdint>

#define S_LEN 4096
#define D_DIM 256

// workspace layout (float offsets)
#define OFF_MINP 0
#define OFF_WPT  16
#define OFF_WTH  (OFF_WPT + 768*256)     // WeffT hi, 768x768 ushort = 294912 floats
#define OFF_WTL  (OFF_WTH + 294912)      // WeffT lo
#define OFF_C    (OFF_WTL + 294912)      // == old OFF_C, downstream unchanged
#define OFF_HH   (OFF_C + 8*768*4096)
#define OFF_V    (OFF_HH + 8*2*256*4096)
#define OFF_U    (OFF_V + 8*256*4096)

// FF weight splits live at the head of the V region (vb is only written by
// k_conv_mfma #1, which runs AFTER k_ff has consumed these — stream-order safe).

typedef __attribute__((ext_vector_type(8))) short short8;
typedef __attribute__((ext_vector_type(4))) float f32x4;

__device__ __forceinline__ unsigned int f2bf(float x) {
    union { float f; unsigned int u; } v; v.f = x;
    unsigned int r = v.u + 0x7fffu + ((v.u >> 16) & 1u);   // RNE
    return r >> 16;
}
__device__ __forceinline__ float bf2f(unsigned int h) {
    union { unsigned int u; float f; } v; v.u = h << 16; return v.f;
}

// ---------------- min valid position per batch ----------------
__global__ __launch_bounds__(256) void k_minpos(const int* __restrict__ pos, float* __restrict__ minp)
{
    const int b = blockIdx.x;
    const int tid = threadIdx.x;
    int mn = 0x7fffffff;
    const int* p = pos + (size_t)b * S_LEN;
    for (int s = tid; s < S_LEN; s += 256) {
        const int v = p[s];
        if (v != -1) mn = min(mn, v);
    }
    __shared__ int red[256];
    red[tid] = mn;
    __syncthreads();
    for (int st = 128; st > 0; st >>= 1) {
        if (tid < st) red[tid] = min(red[tid], red[tid + st]);
        __syncthreads();
    }
    if (tid == 0) minp[b] = (float)red[0];
}

// ---------------- transpose W_proj (256x768) -> WpT (768x256) ----------------
__global__ __launch_bounds__(256) void k_wpt(const float* __restrict__ Wp, float* __restrict__ WpT)
{
    __shared__ float t[32][33];
    const int e0 = blockIdx.x * 32;   // 0..767
    const int d0 = blockIdx.y * 32;   // 0..255
    const int lx = threadIdx.x & 31, ly = threadIdx.x >> 5; // 32x8
#pragma unroll
    for (int q = 0; q < 4; ++q)
        t[ly + 8*q][lx] = Wp[(size_t)(d0 + ly + 8*q) * 768 + e0 + lx];
    __syncthreads();
#pragma unroll
    for (int q = 0; q < 4; ++q)
        WpT[(size_t)(e0 + ly + 8*q) * 256 + d0 + lx] = t[lx][ly + 8*q];
}

// ---------------- generic transpose + bf16 hi/lo split: W[K][N] -> out[N][K] ----------------
__global__ __launch_bounds__(256) void k_tsplit(const float* __restrict__ W, const int K, const int N,
                                                unsigned short* __restrict__ oh, unsigned short* __restrict__ ol)
{
    __shared__ float t[32][33];
    const int n0 = blockIdx.x * 32;
    const int k0 = blockIdx.y * 32;
    const int lx = threadIdx.x & 31, ly = threadIdx.x >> 5;
#pragma unroll
    for (int q = 0; q < 4; ++q)
        t[ly + 8*q][lx] = W[(size_t)(k0 + ly + 8*q) * N + n0 + lx];
    __syncthreads();
#pragma unroll
    for (int q = 0; q < 4; ++q) {
        const float v = t[lx][ly + 8*q];
        const unsigned int h = f2bf(v);
        oh[(size_t)(n0 + ly + 8*q) * K + k0 + lx] = (unsigned short)h;
        ol[(size_t)(n0 + ly + 8*q) * K + k0 + lx] = (unsigned short)f2bf(v - bf2f(h));
    }
}

// ---------------- WeffT[o][t*256+d] = sum_i WpT[g*256+i][d] * conv_w[o][i][t], split hi/lo bf16 ----------------
__global__ __launch_bounds__(256) void k_weff(const float* __restrict__ WpT, const float* __restrict__ cw,
                                              unsigned short* __restrict__ wth, unsigned short* __restrict__ wtl)
{
    const int o = blockIdx.x;       // 768
    const int d = threadIdx.x;      // 256
    const int g = o >> 8;
    __shared__ float cwrow[768];
    for (int i = threadIdx.x; i < 768; i += 256) cwrow[i] = cw[(size_t)o * 768 + i];
    __syncthreads();
    float a0 = 0.f, a1 = 0.f, a2 = 0.f;
    const float* wb = WpT + (size_t)(g * 256) * 256 + d;
#pragma unroll 4
    for (int i = 0; i < 256; ++i) {
        const float wv = wb[(size_t)i * 256];
        a0 += wv * cwrow[i*3+0];
        a1 += wv * cwrow[i*3+1];
        a2 += wv * cwrow[i*3+2];
    }
    const float av[3] = {a0, a1, a2};
#pragma unroll
    for (int t = 0; t < 3; ++t) {
        const unsigned int hb = f2bf(av[t]);
        const unsigned int lb = f2bf(av[t] - bf2f(hb));
        wth[(size_t)o * 768 + t * 256 + d] = (unsigned short)hb;
        wtl[(size_t)o * 768 + t * 256 + d] = (unsigned short)lb;
    }
}

// ---------------- MFMA conv-GEMM (unchanged, verified) ----------------
#define CG_LDA 40
__global__ __launch_bounds__(256, 2) void k_convgemm(
    const float* __restrict__ emb, const int* __restrict__ pos,
    const unsigned short* __restrict__ wth, const unsigned short* __restrict__ wtl,
    const float* __restrict__ convb, float* __restrict__ c)
{
    const int b  = blockIdx.z;
    const int o0 = blockIdx.y * 128;
    const int s0 = blockIdx.x * 128;
    const int tid  = threadIdx.x;
    const int wave = tid >> 6, lane = tid & 63;
    const int m16  = lane & 15, quad = lane >> 4;

    __shared__ __align__(16) unsigned short Ah[130 * CG_LDA];
    __shared__ __align__(16) unsigned short Al[130 * CG_LDA];
    __shared__ __align__(16) unsigned short Bh[128 * CG_LDA];
    __shared__ __align__(16) unsigned short Bl[128 * CG_LDA];

    f32x4 acc[2][8];
#pragma unroll
    for (int mt = 0; mt < 2; ++mt)
#pragma unroll
        for (int nt = 0; nt < 8; ++nt)
#pragma unroll
            for (int e = 0; e < 4; ++e) acc[mt][nt][e] = 0.f;

    for (int c8 = 0; c8 < 8; ++c8) {
        for (int t = 0; t < 3; ++t) {
            if (t == 0) {
                for (int task = tid; task < 1040; task += 256) {
                    const int r = task >> 3;
                    const int g = task & 7;
                    const int srow = s0 + r - 1;
                    float4 v = make_float4(0.f, 0.f, 0.f, 0.f);
                    if (srow >= 0 && srow < S_LEN)
                        v = *(const float4*)(emb + ((size_t)b * S_LEN + srow) * D_DIM + c8 * 32 + g * 4);
                    const unsigned int hx = f2bf(v.x), hy = f2bf(v.y), hz = f2bf(v.z), hw = f2bf(v.w);
                    uint2 hp, lp;
                    hp.x = hx | (hy << 16);
                    hp.y = hz | (hw << 16);
                    lp.x = f2bf(v.x - bf2f(hx)) | (f2bf(v.y - bf2f(hy)) << 16);
                    lp.y = f2bf(v.z - bf2f(hz)) | (f2bf(v.w - bf2f(hw)) << 16);
                    *(uint2*)&Ah[r * CG_LDA + g * 4] = hp;
                    *(uint2*)&Al[r * CG_LDA + g * 4] = lp;
                }
            }
            for (int task = tid; task < 512; task += 256) {
                const int r = task >> 2;
                const int g = task & 3;
                const size_t gi = (size_t)(o0 + r) * 768 + t * 256 + c8 * 32 + g * 8;
                *(uint4*)&Bh[r * CG_LDA + g * 8] = *(const uint4*)(wth + gi);
                *(uint4*)&Bl[r * CG_LDA + g * 8] = *(const uint4*)(wtl + gi);
            }
            __syncthreads();
            short8 ah[2], al[2];
#pragma unroll
            for (int mt = 0; mt < 2; ++mt) {
                const int ar = (wave * 32 + mt * 16 + m16 + t) * CG_LDA + quad * 8;
                ah[mt] = *(const short8*)&Ah[ar];
                al[mt] = *(const short8*)&Al[ar];
            }
#pragma unroll
            for (int nt = 0; nt < 8; ++nt) {
                const int br = (nt * 16 + m16) * CG_LDA + quad * 8;
                const short8 bh = *(const short8*)&Bh[br];
                const short8 bl = *(const short8*)&Bl[br];
#pragma unroll
                for (int mt = 0; mt < 2; ++mt) {
                    acc[mt][nt] = __builtin_amdgcn_mfma_f32_16x16x32_bf16(ah[mt], bh, acc[mt][nt], 0, 0, 0);
                    acc[mt][nt] = __builtin_amdgcn_mfma_f32_16x16x32_bf16(ah[mt], bl, acc[mt][nt], 0, 0, 0);
                    acc[mt][nt] = __builtin_amdgcn_mfma_f32_16x16x32_bf16(al[mt], bh, acc[mt][nt], 0, 0, 0);
                }
            }
            __syncthreads();
        }
    }

    float msk[2][4];
#pragma unroll
    for (int mt = 0; mt < 2; ++mt) {
        const int s = s0 + wave * 32 + mt * 16 + quad * 4;
        const int4 p4 = *(const int4*)(pos + (size_t)b * S_LEN + s);
        msk[mt][0] = (p4.x != -1) ? 1.f : 0.f;
        msk[mt][1] = (p4.y != -1) ? 1.f : 0.f;
        msk[mt][2] = (p4.z != -1) ? 1.f : 0.f;
        msk[mt][3] = (p4.w != -1) ? 1.f : 0.f;
    }
#pragma unroll
    for (int nt = 0; nt < 8; ++nt) {
        const int o = o0 + nt * 16 + m16;
        const float cb = convb[o];
#pragma unroll
        for (int mt = 0; mt < 2; ++mt) {
            const int s = s0 + wave * 32 + mt * 16 + quad * 4;
            float4 r;
            r.x = (acc[mt][nt][0] + cb) * msk[mt][0];
            r.y = (acc[mt][nt][1] + cb) * msk[mt][1];
            r.z = (acc[mt][nt][2] + cb) * msk[mt][2];
            r.w = (acc[mt][nt][3] + cb) * msk[mt][3];
            *(float4*)(c + ((size_t)(b * 768 + o)) * S_LEN + s) = r;
        }
    }
}

// ---------------- RoPE + FF (MFMA, LDS-staged B) + L1-normalize -> hh[b][i][d][s] ----------------
// 64 s-rows per block, 4 waves; wave w owns rows [16w,16w+16). 3-pass bf16-split MFMA.
// B (weights) staged through LDS in 8KB [16N][128k] tiles, reg-double-buffered (T14):
// next tile's global loads issue before current tile's MFMAs. A-frags hoisted per k-half.
#define FF_LDA 264   // 256 + 8 ushort pad: rows 528B apart (33*16B, 2-way banks = free)
#define FF_LDB 136   // 128 + 8 pad: rows 272B apart (17*16B)
__global__ __launch_bounds__(256, 2) void k_ff(
    const float* __restrict__ emb, const int* __restrict__ pos, const float* __restrict__ minp,
    const unsigned short* __restrict__ w1th, const unsigned short* __restrict__ w1tl,
    const float* __restrict__ b1,
    const float* __restrict__ lng, const float* __restrict__ lnb,
    const unsigned short* __restrict__ w2th, const unsigned short* __restrict__ w2tl,
    const float* __restrict__ b2, const float* __restrict__ ffs, float* __restrict__ hh)
{
    const int b   = blockIdx.y;
    const int s0  = blockIdx.x * 64;
    const int tid = threadIdx.x;
    const int wave = tid >> 6, lane = tid & 63;
    const int m16  = lane & 15, quad = lane >> 4;

    __shared__ __align__(16) unsigned short Th[64 * FF_LDA];
    __shared__ __align__(16) unsigned short Tl[64 * FF_LDA];
    __shared__ __align__(16) unsigned short Bsh[16 * FF_LDB];
    __shared__ __align__(16) unsigned short Bsl[16 * FF_LDB];
    __shared__ float th_s[128];

    if (tid < 128) th_s[tid] = expf(-(float)tid * 0.07195578415606394f);
    __syncthreads();

    // ---- RoPE -> Th/Tl (each thread: 1/4 of one row = 64 cols = 32 pairs) ----
    {
        const int r    = tid >> 2;            // 0..63
        const int col0 = (tid & 3) * 64;
        const int s    = s0 + r;
        const int p    = pos[(size_t)b * S_LEN + s];
        const float adj = (p == -1) ? -1.f : ((float)p - minp[b]);
        const float* ep = emb + ((size_t)b * S_LEN + s) * D_DIM;
#pragma unroll
        for (int p8 = 0; p8 < 8; ++p8) {
            const int cbase = col0 + p8 * 8;
            const float4 va = *(const float4*)(ep + cbase);
            const float4 vb4 = *(const float4*)(ep + cbase + 4);
            const float x[8] = {va.x, va.y, va.z, va.w, vb4.x, vb4.y, vb4.z, vb4.w};
            unsigned int uh[4], ul[4];
#pragma unroll
            for (int jj = 0; jj < 4; ++jj) {
                const int j = (cbase >> 1) + jj;
                const float theta = th_s[j];
                float sn, cs;
                sincosf(adj * theta, &sn, &cs);
                const float x1 = x[2*jj], x2 = x[2*jj+1];
                const float r1 = x1 * cs - x2 * sn;
                const float r2 = x1 * sn + x2 * cs;
                const unsigned int h1 = f2bf(r1), h2 = f2bf(r2);
                uh[jj] = h1 | (h2 << 16);
                ul[jj] = f2bf(r1 - bf2f(h1)) | (f2bf(r2 - bf2f(h2)) << 16);
            }
            uint4 wh, wl;
            wh.x = uh[0]; wh.y = uh[1]; wh.z = uh[2]; wh.w = uh[3];
            wl.x = ul[0]; wl.y = ul[1]; wl.z = ul[2]; wl.w = ul[3];
            *(uint4*)&Th[r * FF_LDA + cbase] = wh;
            *(uint4*)&Tl[r * FF_LDA + cbase] = wl;
        }
    }
    __syncthreads();

    const int rowA  = wave * 16 + m16;
    const int strow = tid >> 4;           // staging: row 0..15
    const int stks  = (tid & 15) * 8;     // staging: k-segment

    // ---- GEMM1: H[64x256] = T @ W1 (3-pass split, LDS-staged B, reg-dbuf) ----
    f32x4 acc1[16];
#pragma unroll
    for (int nt = 0; nt < 16; ++nt)
#pragma unroll
        for (int e = 0; e < 4; ++e) acc1[nt][e] = 0.f;

    uint4 pfh, pfl;
    {
        const size_t gi = (size_t)strow * 256 + stks;   // nt=0, kh=0
        pfh = *(const uint4*)(w1th + gi);
        pfl = *(const uint4*)(w1tl + gi);
    }
    for (int kh = 0; kh < 2; ++kh) {
        short8 a1h[4], a1l[4];
#pragma unroll
        for (int c4 = 0; c4 < 4; ++c4) {
            const int ar = rowA * FF_LDA + kh * 128 + c4 * 32 + quad * 8;
            a1h[c4] = *(const short8*)&Th[ar];
            a1l[c4] = *(const short8*)&Tl[ar];
        }
#pragma unroll
        for (int nt = 0; nt < 16; ++nt) {
            __syncthreads();   // previous tile's consumers done
            *(uint4*)&Bsh[strow * FF_LDB + stks] = pfh;
            *(uint4*)&Bsl[strow * FF_LDB + stks] = pfl;
            if (!(kh == 1 && nt == 15)) {
                const int nt2 = (nt + 1) & 15;
                const int kh2 = kh + (nt == 15);
                const size_t gi = (size_t)(nt2 * 16 + strow) * 256 + kh2 * 128 + stks;
                pfh = *(const uint4*)(w1th + gi);
                pfl = *(const uint4*)(w1tl + gi);
            }
            __syncthreads();   // tile ready
#pragma unroll
            for (int c4 = 0; c4 < 4; ++c4) {
                const int br = m16 * FF_LDB + c4 * 32 + quad * 8;
                const short8 bh = *(const short8*)&Bsh[br];
                const short8 bl = *(const short8*)&Bsl[br];
                acc1[nt] = __builtin_amdgcn_mfma_f32_16x16x32_bf16(a1h[c4], bh, acc1[nt], 0, 0, 0);
                acc1[nt] = __builtin_amdgcn_mfma_f32_16x16x32_bf16(a1h[c4], bl, acc1[nt], 0, 0, 0);
                acc1[nt] = __builtin_amdgcn_mfma_f32_16x16x32_bf16(a1l[c4], bh, acc1[nt], 0, 0, 0);
            }
        }
    }

    // ---- +b1, LayerNorm stats (in-register, shfl over m16 group) ----
    float sume[4] = {0.f, 0.f, 0.f, 0.f}, sumq[4] = {0.f, 0.f, 0.f, 0.f};
#pragma unroll
    for (int nt = 0; nt < 16; ++nt) {
        const float bb = b1[nt * 16 + m16];
#pragma unroll
        for (int e = 0; e < 4; ++e) {
            const float v = acc1[nt][e] + bb;
            acc1[nt][e] = v;
            sume[e] += v;
            sumq[e] += v * v;
        }
    }
#pragma unroll
    for (int e = 0; e < 4; ++e) {
#pragma unroll
        for (int off = 1; off < 16; off <<= 1) {
            sume[e] += __shfl_xor(sume[e], off, 64);
            sumq[e] += __shfl_xor(sumq[e], off, 64);
        }
    }
    float mu[4], rs[4];
#pragma unroll
    for (int e = 0; e < 4; ++e) {
        mu[e] = sume[e] * (1.f / 256.f);
        const float var = sumq[e] * (1.f / 256.f) - mu[e] * mu[e];
        rs[e] = rsqrtf(var + 1e-5f);
    }

    // preload GEMM2 tile (0,0) while LN finishes
    {
        const size_t gi = (size_t)strow * 256 + stks;
        pfh = *(const uint4*)(w2th + gi);
        pfl = *(const uint4*)(w2tl + gi);
    }

    // ---- LN + GELU + split, write H back into Th/Tl ----
    __syncthreads();   // all waves done reading T / Bs
#pragma unroll
    for (int nt = 0; nt < 16; ++nt) {
        const int col = nt * 16 + m16;
        const float g  = lng[col];
        const float be = lnb[col];
#pragma unroll
        for (int e = 0; e < 4; ++e) {
            const float h  = (acc1[nt][e] - mu[e]) * rs[e] * g + be;
            const float hg = 0.5f * h * (1.f + erff(h * 0.7071067811865475f));
            const unsigned int hb = f2bf(hg);
            const int li = (wave * 16 + quad * 4 + e) * FF_LDA + col;
            Th[li] = (unsigned short)hb;
            Tl[li] = (unsigned short)f2bf(hg - bf2f(hb));
        }
    }
    __syncthreads();

    // ---- GEMM2: A[64x512] = Hg @ W2 (3-pass split, LDS-staged B, reg-dbuf) ----
    f32x4 acc2[32];
#pragma unroll
    for (int nt = 0; nt < 32; ++nt)
#pragma unroll
        for (int e = 0; e < 4; ++e) acc2[nt][e] = 0.f;

    for (int kh = 0; kh < 2; ++kh) {
        short8 a2h[4], a2l[4];
#pragma unroll
        for (int c4 = 0; c4 < 4; ++c4) {
            const int ar = rowA * FF_LDA + kh * 128 + c4 * 32 + quad * 8;
            a2h[c4] = *(const short8*)&Th[ar];
            a2l[c4] = *(const short8*)&Tl[ar];
        }
#pragma unroll
        for (int nt = 0; nt < 32; ++nt) {
            __syncthreads();
            *(uint4*)&Bsh[strow * FF_LDB + stks] = pfh;
            *(uint4*)&Bsl[strow * FF_LDB + stks] = pfl;
            if (!(kh == 1 && nt == 31)) {
                const int nt2 = (nt + 1) & 31;
                const int kh2 = kh + (nt == 31);
                const size_t gi = (size_t)(nt2 * 16 + strow) * 256 + kh2 * 128 + stks;
                pfh = *(const uint4*)(w2th + gi);
                pfl = *(const uint4*)(w2tl + gi);
            }
            __syncthreads();
#pragma unroll
            for (int c4 = 0; c4 < 4; ++c4) {
                const int br = m16 * FF_LDB + c4 * 32 + quad * 8;
                const short8 bh = *(const short8*)&Bsh[br];
                const short8 bl = *(const short8*)&Bsl[br];
                acc2[nt] = __builtin_amdgcn_mfma_f32_16x16x32_bf16(a2h[c4], bh, acc2[nt], 0, 0, 0);
                acc2[nt] = __builtin_amdgcn_mfma_f32_16x16x32_bf16(a2h[c4], bl, acc2[nt], 0, 0, 0);
                acc2[nt] = __builtin_amdgcn_mfma_f32_16x16x32_bf16(a2l[c4], bh, acc2[nt], 0, 0, 0);
            }
        }
    }

    // ---- (a+b2)*ffs, L1-norm per (row, half), store hh[b][i][d][s] ----
    float sm[2][4] = {{0.f,0.f,0.f,0.f},{0.f,0.f,0.f,0.f}};
#pragma unroll
    for (int nt = 0; nt < 32; ++nt) {
        const int col = nt * 16 + m16;
        const float bb = b2[col];
        const float fs = ffs[col];
#pragma unroll
        for (int e = 0; e < 4; ++e) {
            const float v = (acc2[nt][e] + bb) * fs;
            acc2[nt][e] = v;
            sm[nt >> 4][e] += fabsf(v);
        }
    }
#pragma unroll
    for (int i = 0; i < 2; ++i)
#pragma unroll
        for (int e = 0; e < 4; ++e) {
#pragma unroll
            for (int off = 1; off < 16; off <<= 1)
                sm[i][e] += __shfl_xor(sm[i][e], off, 64);
        }
#pragma unroll
    for (int nt = 0; nt < 32; ++nt) {
        const int i = nt >> 4;
        const int d = (nt & 15) * 16 + m16;
        float4 o4;
        o4.x = acc2[nt][0] / (sm[i][0] + 1e-8f);
        o4.y = acc2[nt][1] / (sm[i][1] + 1e-8f);
        o4.z = acc2[nt][2] / (sm[i][2] + 1e-8f);
        o4.w = acc2[nt][3] / (sm[i][3] + 1e-8f);
        *(float4*)(hh + ((size_t)((b * 2 + i) * 256 + d)) * S_LEN + s0 + wave * 16 + quad * 4) = o4;
    }
}

// ---------------- MFMA blocked-Toeplitz causal long conv (unchanged) ----------------
#define XS_PAD   960
#define XS_ELEMS 5056
#define FRX_WORDS 4160
__device__ __forceinline__ int xsw(int blk) { return blk ^ ((blk >> 3) & 7); }

__global__ __launch_bounds__(64) void k_conv_mfma(
    const float* __restrict__ xbuf, const int xC, const int xoff,
    const float* __restrict__ hh, const int iord,
    const float* __restrict__ cbuf, float* __restrict__ outb)
{
    const int d = blockIdx.x;
    const int b = blockIdx.y;
    const int lane = threadIdx.x;
    const float* xp = xbuf + ((size_t)(b * xC + xoff + d)) * S_LEN;
    const float* fp = hh   + ((size_t)((b * 2 + iord) * 256 + d)) * S_LEN;
    const float* zp = cbuf + ((size_t)(b * 768 + iord * 256 + d)) * S_LEN;
    float* op = outb + ((size_t)(b * 256 + d)) * S_LEN;

    __shared__ unsigned short xs[XS_ELEMS];
    __shared__ unsigned int   frx[FRX_WORDS];

    {
        for (int blk = lane; blk < 120; blk += 64) {
            int4 z; z.x = 0; z.y = 0; z.z = 0; z.w = 0;
            *(int4*)(xs + xsw(blk) * 8) = z;
        }
#pragma unroll
        for (int it = 0; it < 8; ++it) {
            const int idx = it * 64 + lane;
            const int j = idx * 8;
            const float4 v0 = *(const float4*)(xp + j);
            const float4 v1 = *(const float4*)(xp + j + 4);
            int4 w;
            w.x = (int)(f2bf(v0.x) | (f2bf(v0.y) << 16));
            w.y = (int)(f2bf(v0.z) | (f2bf(v0.w) << 16));
            w.z = (int)(f2bf(v1.x) | (f2bf(v1.y) << 16));
            w.w = (int)(f2bf(v1.z) | (f2bf(v1.w) << 16));
            *(int4*)(xs + xsw(120 + idx) * 8) = w;
        }
    }
    {
        frx[4096 + lane] = 0u;
        if (lane == 0) frx[4095] = f2bf(fp[0]);
#pragma unroll
        for (int it = 0; it < 16; ++it) {
            const int j = (it * 64 + lane) * 4;
            const float4 v = *(const float4*)(fp + j);
            const float f4 = (j + 4 < S_LEN) ? fp[j + 4] : 0.f;
            frx[4094 - j] = f2bf(v.y) | (f2bf(v.x) << 16);
            frx[4093 - j] = f2bf(v.z) | (f2bf(v.y) << 16);
            frx[4092 - j] = f2bf(v.w) | (f2bf(v.z) << 16);
            if (j < 4092) frx[4091 - j] = f2bf(f4) | (f2bf(v.w) << 16);
        }
    }
    __syncthreads();

    const int m    = lane & 15;
    const int quad = lane >> 4;

    f32x4 acc[4][4];
#pragma unroll
    for (int mt = 0; mt < 4; ++mt)
#pragma unroll
        for (int pt = 0; pt < 4; ++pt)
#pragma unroll
            for (int e = 0; e < 4; ++e) acc[mt][pt][e] = 0.f;

    const int eA_base = 4095 - m + quad * 8;
    const int oB_base = XS_PAD + 64 * m + quad * 8;

    for (int r = 0; r < 64; ++r) {
        const int ea_r = eA_base - 64 * r;
        short8 afr[4][2];
#pragma unroll
        for (int mt = 0; mt < 4; ++mt)
#pragma unroll
            for (int kc = 0; kc < 2; ++kc) {
                const int e = ea_r - 16 * mt + 32 * kc;
                union { unsigned int u[4]; short8 s; } cvt;
                cvt.u[0] = frx[e];
                cvt.u[1] = frx[e + 2];
                cvt.u[2] = frx[e + 4];
                cvt.u[3] = frx[e + 6];
                afr[mt][kc] = cvt.s;
            }
        const int ptmin = r >> 4;
        const int ob_r = oB_base - 64 * r;
#pragma unroll
        for (int pt = 0; pt < 4; ++pt) {
            if (pt >= ptmin) {
                const int o0 = ob_r + 1024 * pt;
                const short8 bfr0 = *(const short8*)(xs + xsw(o0 >> 3) * 8);
                const short8 bfr1 = *(const short8*)(xs + xsw((o0 + 32) >> 3) * 8);
#pragma unroll
                for (int mt = 0; mt < 4; ++mt) {
                    acc[mt][pt] = __builtin_amdgcn_mfma_f32_16x16x32_bf16(afr[mt][0], bfr0, acc[mt][pt], 0, 0, 0);
                    acc[mt][pt] = __builtin_amdgcn_mfma_f32_16x16x32_bf16(afr[mt][1], bfr1, acc[mt][pt], 0, 0, 0);
                }
            }
        }
    }

    const float inv = 1.f / 8192.f;
#pragma unroll
    for (int mt = 0; mt < 4; ++mt)
#pragma unroll
        for (int pt = 0; pt < 4; ++pt) {
            const int p  = 16 * pt + m;
            const int s0 = 64 * p + 16 * mt + quad * 4;
            const float4 z4 = *(const float4*)(zp + s0);
            float4 o4;
            o4.x = z4.x * acc[mt][pt][0] * inv;
            o4.y = z4.y * acc[mt][pt][1] * inv;
            o4.z = z4.z * acc[mt][pt][2] * inv;
            o4.w = z4.w * acc[mt][pt][3] * inv;
            *(float4*)(op + s0) = o4;
        }
}

// ---------------- out[b][s][e] = mask * (sum_d v[b][d][s] * W_out[d][e] + b_out[e]) ----------------
__global__ __launch_bounds__(256) void k_out(
    const float* __restrict__ v, const float* __restrict__ Wo,
    const float* __restrict__ bo, const int* __restrict__ pos,
    float* __restrict__ out)
{
    const int b   = blockIdx.y;
    const int s0  = blockIdx.x * 32;
    const int tid = threadIdx.x;
    __shared__ float vs[256 * 36];
    {
        const float4* src = (const float4*)(v + ((size_t)(b*256 + tid)) * S_LEN + s0);
#pragma unroll
        for (int q = 0; q < 8; ++q) {
            *(float4*)&vs[tid*36 + q*4] = src[q];
        }
    }
    __syncthreads();
    float acc[32];
#pragma unroll
    for (int r = 0; r < 32; ++r) acc[r] = 0.f;
    for (int dd = 0; dd < 256; ++dd) {
        const float w = Wo[(size_t)dd * 256 + tid];
        const float* vr = &vs[dd * 36];
#pragma unroll
        for (int q = 0; q < 8; ++q) {
            const float4 x4 = *(const float4*)&vr[q*4];
            acc[q*4+0] += x4.x * w;
            acc[q*4+1] += x4.y * w;
            acc[q*4+2] += x4.z * w;
            acc[q*4+3] += x4.w * w;
        }
    }
    const float bb = bo[tid];
#pragma unroll
    for (int r = 0; r < 32; ++r) {
        const int s = s0 + r;
        const float m = (pos[(size_t)b * S_LEN + s] != -1) ? 1.f : 0.f;
        out[((size_t)b * S_LEN + s) * 256 + tid] = (acc[r] + bb) * m;
    }
}

extern "C" void kernel_launch(void* const* d_in, const int* in_sizes, int n_in,
                              void* d_out, int out_size, void* d_ws, size_t ws_size,
                              hipStream_t stream) {
    const float* emb = (const float*)d_in[0];
    const int*   pos = (const int*)  d_in[1];
    const float* Wp  = (const float*)d_in[2];
    const float* cw  = (const float*)d_in[3];
    const float* cb  = (const float*)d_in[4];
    const float* W1  = (const float*)d_in[5];
    const float* b1  = (const float*)d_in[6];
    const float* lg  = (const float*)d_in[7];
    const float* lb  = (const float*)d_in[8];
    const float* W2  = (const float*)d_in[9];
    const float* b2  = (const float*)d_in[10];
    const float* ffs = (const float*)d_in[11];
    const float* Wo  = (const float*)d_in[12];
    const float* bo  = (const float*)d_in[13];

    float* ws   = (float*)d_ws;
    float* minp = ws + OFF_MINP;
    float* wpt  = ws + OFF_WPT;
    unsigned short* wth = (unsigned short*)(ws + OFF_WTH);
    unsigned short* wtl = (unsigned short*)(ws + OFF_WTL);
    float* c    = ws + OFF_C;
    float* hh   = ws + OFF_HH;
    float* vb   = ws + OFF_V;
    float* ub   = ws + OFF_U;

    // FF weight splits carved from the head of vb (consumed by k_ff before conv#1 writes vb)
    unsigned short* w1th = (unsigned short*)vb;
    unsigned short* w1tl = w1th + 256 * 256;
    unsigned short* w2th = w1tl + 256 * 256;
    unsigned short* w2tl = w2th + 512 * 256;

    k_minpos<<<dim3(8), dim3(256), 0, stream>>>(pos, minp);
    k_wpt<<<dim3(24, 8), dim3(256), 0, stream>>>(Wp, wpt);
    k_weff<<<dim3(768), dim3(256), 0, stream>>>(wpt, cw, wth, wtl);
    k_tsplit<<<dim3(8, 8), dim3(256), 0, stream>>>(W1, 256, 256, w1th, w1tl);
    k_tsplit<<<dim3(16, 8), dim3(256), 0, stream>>>(W2, 256, 512, w2th, w2tl);
    k_convgemm<<<dim3(32, 6, 8), dim3(256), 0, stream>>>(emb, pos, wth, wtl, cb, c);
    k_ff<<<dim3(64, 8), dim3(256), 0, stream>>>(emb, pos, minp, w1th, w1tl, b1, lg, lb, w2th, w2tl, b2, ffs, hh);
    // v = zs[2]; v = zs[0] * longconv(v, hh[:,0]); v = zs[1] * longconv(v, hh[:,1])
    k_conv_mfma<<<dim3(256, 8), dim3(64), 0, stream>>>(c, 768, 512, hh, 0, c, vb);
    k_conv_mfma<<<dim3(256, 8), dim3(64), 0, stream>>>(vb, 256, 0, hh, 1, c, ub);
    k_out<<<dim3(128, 8), dim3(256), 0, stream>>>(ub, Wo, bo, pos, (float*)d_out);
}

// Round 4
// 533.567 us; speedup vs baseline: 1.5641x; 1.0835x over previous
//
#include <hip/hip_runtime.h>
#include <cstdint>

#define S_LEN 4096
#define D_DIM 256

// workspace layout (float offsets)
#define OFF_MINP 0
#define OFF_WPT  16
#define OFF_WTH  (OFF_WPT + 768*256)     // WeffT hi, 768x768 ushort = 294912 floats
#define OFF_WTL  (OFF_WTH + 294912)      // WeffT lo
#define OFF_C    (OFF_WTL + 294912)      // == old OFF_C, downstream unchanged
#define OFF_HH   (OFF_C + 8*768*4096)
#define OFF_V    (OFF_HH + 8*2*256*4096)
#define OFF_U    (OFF_V + 8*256*4096)

// FF weight splits live at the head of the V region (vb is only written by
// k_conv_mfma #1, which runs AFTER k_ff has consumed these — stream-order safe).

typedef __attribute__((ext_vector_type(8))) short short8;
typedef __attribute__((ext_vector_type(4))) float f32x4;

__device__ __forceinline__ unsigned int f2bf(float x) {
    union { float f; unsigned int u; } v; v.f = x;
    unsigned int r = v.u + 0x7fffu + ((v.u >> 16) & 1u);   // RNE
    return r >> 16;
}
__device__ __forceinline__ float bf2f(unsigned int h) {
    union { unsigned int u; float f; } v; v.u = h << 16; return v.f;
}

// ---------------- min valid position per batch ----------------
__global__ __launch_bounds__(256) void k_minpos(const int* __restrict__ pos, float* __restrict__ minp)
{
    const int b = blockIdx.x;
    const int tid = threadIdx.x;
    int mn = 0x7fffffff;
    const int* p = pos + (size_t)b * S_LEN;
    for (int s = tid; s < S_LEN; s += 256) {
        const int v = p[s];
        if (v != -1) mn = min(mn, v);
    }
    __shared__ int red[256];
    red[tid] = mn;
    __syncthreads();
    for (int st = 128; st > 0; st >>= 1) {
        if (tid < st) red[tid] = min(red[tid], red[tid + st]);
        __syncthreads();
    }
    if (tid == 0) minp[b] = (float)red[0];
}

// ---------------- transpose W_proj (256x768) -> WpT (768x256) ----------------
__global__ __launch_bounds__(256) void k_wpt(const float* __restrict__ Wp, float* __restrict__ WpT)
{
    __shared__ float t[32][33];
    const int e0 = blockIdx.x * 32;   // 0..767
    const int d0 = blockIdx.y * 32;   // 0..255
    const int lx = threadIdx.x & 31, ly = threadIdx.x >> 5; // 32x8
#pragma unroll
    for (int q = 0; q < 4; ++q)
        t[ly + 8*q][lx] = Wp[(size_t)(d0 + ly + 8*q) * 768 + e0 + lx];
    __syncthreads();
#pragma unroll
    for (int q = 0; q < 4; ++q)
        WpT[(size_t)(e0 + ly + 8*q) * 256 + d0 + lx] = t[lx][ly + 8*q];
}

// ---------------- generic transpose + bf16 hi/lo split: W[K][N] -> out[N][K] ----------------
__global__ __launch_bounds__(256) void k_tsplit(const float* __restrict__ W, const int K, const int N,
                                                unsigned short* __restrict__ oh, unsigned short* __restrict__ ol)
{
    __shared__ float t[32][33];
    const int n0 = blockIdx.x * 32;
    const int k0 = blockIdx.y * 32;
    const int lx = threadIdx.x & 31, ly = threadIdx.x >> 5;
#pragma unroll
    for (int q = 0; q < 4; ++q)
        t[ly + 8*q][lx] = W[(size_t)(k0 + ly + 8*q) * N + n0 + lx];
    __syncthreads();
#pragma unroll
    for (int q = 0; q < 4; ++q) {
        const float v = t[lx][ly + 8*q];
        const unsigned int h = f2bf(v);
        oh[(size_t)(n0 + ly + 8*q) * K + k0 + lx] = (unsigned short)h;
        ol[(size_t)(n0 + ly + 8*q) * K + k0 + lx] = (unsigned short)f2bf(v - bf2f(h));
    }
}

// ---------------- WeffT[o][t*256+d] = sum_i WpT[g*256+i][d] * conv_w[o][i][t], split hi/lo bf16 ----------------
__global__ __launch_bounds__(256) void k_weff(const float* __restrict__ WpT, const float* __restrict__ cw,
                                              unsigned short* __restrict__ wth, unsigned short* __restrict__ wtl)
{
    const int o = blockIdx.x;       // 768
    const int d = threadIdx.x;      // 256
    const int g = o >> 8;
    __shared__ float cwrow[768];
    for (int i = threadIdx.x; i < 768; i += 256) cwrow[i] = cw[(size_t)o * 768 + i];
    __syncthreads();
    float a0 = 0.f, a1 = 0.f, a2 = 0.f;
    const float* wb = WpT + (size_t)(g * 256) * 256 + d;
#pragma unroll 4
    for (int i = 0; i < 256; ++i) {
        const float wv = wb[(size_t)i * 256];
        a0 += wv * cwrow[i*3+0];
        a1 += wv * cwrow[i*3+1];
        a2 += wv * cwrow[i*3+2];
    }
    const float av[3] = {a0, a1, a2};
#pragma unroll
    for (int t = 0; t < 3; ++t) {
        const unsigned int hb = f2bf(av[t]);
        const unsigned int lb = f2bf(av[t] - bf2f(hb));
        wth[(size_t)o * 768 + t * 256 + d] = (unsigned short)hb;
        wtl[(size_t)o * 768 + t * 256 + d] = (unsigned short)lb;
    }
}

// ---------------- MFMA conv-GEMM: c[b][o][s] = mask*(conv_b[o] + sum_{t,d} emb[b][s+t-1][d]*Weff[t][d][o]) ----
// 2-pass split (A plain bf16 RNE, B hi/lo: acc += Ah*Bh + Ah*Bl), reg-prefetched staging:
// A-tile (c8+1) and B-tile (next segment) global loads issue before the current MFMA phase,
// so the staging phase between barriers is LDS-writes-only.
#define CG_LDA 40   // 32 + 8 pad (16B frag alignment preserved: 80B rows)
__global__ __launch_bounds__(256, 3) void k_convgemm(
    const float* __restrict__ emb, const int* __restrict__ pos,
    const unsigned short* __restrict__ wth, const unsigned short* __restrict__ wtl,
    const float* __restrict__ convb, float* __restrict__ c)
{
    const int b  = blockIdx.z;
    const int o0 = blockIdx.y * 128;
    const int s0 = blockIdx.x * 128;
    const int tid  = threadIdx.x;
    const int wave = tid >> 6, lane = tid & 63;
    const int m16  = lane & 15, quad = lane >> 4;

    __shared__ __align__(16) unsigned short As[130 * CG_LDA];
    __shared__ __align__(16) unsigned short Bh[128 * CG_LDA];
    __shared__ __align__(16) unsigned short Bl[128 * CG_LDA];

    // A staging: thread -> row rA = tid>>1 (0..127), 16 consecutive k-cols at cA
    const int rA = tid >> 1;
    const int cA = (tid & 1) * 16;
    const int srowA = s0 + rA - 1;
    const bool vA = (srowA >= 0 && srowA < S_LEN);
    const float* embA = emb + ((size_t)b * S_LEN + (vA ? srowA : 0)) * D_DIM + cA;
    // A tail rows 128..129: threads 0..15, 4 k-cols each
    const int rT = 128 + (tid >> 3);
    const int cT = (tid & 7) * 4;
    const int srowT = s0 + rT - 1;
    const bool vT = (tid < 16) && (srowT >= 0 && srowT < S_LEN);
    const float* embT = emb + ((size_t)b * S_LEN + ((tid < 16 && vT) ? srowT : 0)) * D_DIM + cT;

    // B staging: tasks {tid, tid+256}: row task>>2, 8 k-cols at (task&3)*8
    const int rB0 = tid >> 2,        gB0 = (tid & 3) * 8;
    const int rB1 = 64 + (tid >> 2), gB1 = gB0;

    float4 apf[4]; float4 apfT;
    uint4 bph0, bpl0, bph1, bpl1;

    // preload A(c8=0) and B(seg 0: t=0,c8=0)
#pragma unroll
    for (int q = 0; q < 4; ++q) apf[q] = vA ? *(const float4*)(embA + q * 4) : make_float4(0.f,0.f,0.f,0.f);
    apfT = vT ? *(const float4*)(embT) : make_float4(0.f,0.f,0.f,0.f);
    {
        const size_t gi0 = (size_t)(o0 + rB0) * 768 + gB0;
        const size_t gi1 = (size_t)(o0 + rB1) * 768 + gB1;
        bph0 = *(const uint4*)(wth + gi0); bpl0 = *(const uint4*)(wtl + gi0);
        bph1 = *(const uint4*)(wth + gi1); bpl1 = *(const uint4*)(wtl + gi1);
    }

    f32x4 acc[2][8];
#pragma unroll
    for (int mt = 0; mt < 2; ++mt)
#pragma unroll
        for (int nt = 0; nt < 8; ++nt)
#pragma unroll
            for (int e = 0; e < 4; ++e) acc[mt][nt][e] = 0.f;

    for (int c8 = 0; c8 < 8; ++c8) {
        for (int t = 0; t < 3; ++t) {
            __syncthreads();   // consumers of previous tiles done
            if (t == 0) {
                // write A (bf16 RNE) from prefetch regs
#pragma unroll
                for (int q = 0; q < 4; ++q) {
                    const float4 v = apf[q];
                    uint2 hp;
                    hp.x = f2bf(v.x) | (f2bf(v.y) << 16);
                    hp.y = f2bf(v.z) | (f2bf(v.w) << 16);
                    *(uint2*)&As[rA * CG_LDA + cA + q * 4] = hp;
                }
                if (tid < 16) {
                    const float4 v = apfT;
                    uint2 hp;
                    hp.x = f2bf(v.x) | (f2bf(v.y) << 16);
                    hp.y = f2bf(v.z) | (f2bf(v.w) << 16);
                    *(uint2*)&As[rT * CG_LDA + cT] = hp;
                }
                if (c8 < 7) {
                    const int base = (c8 + 1) * 32;
#pragma unroll
                    for (int q = 0; q < 4; ++q) apf[q] = vA ? *(const float4*)(embA + base + q * 4) : make_float4(0.f,0.f,0.f,0.f);
                    apfT = vT ? *(const float4*)(embT + base) : make_float4(0.f,0.f,0.f,0.f);
                }
            }
            // write B from prefetch regs
            *(uint4*)&Bh[rB0 * CG_LDA + gB0] = bph0;
            *(uint4*)&Bl[rB0 * CG_LDA + gB0] = bpl0;
            *(uint4*)&Bh[rB1 * CG_LDA + gB1] = bph1;
            *(uint4*)&Bl[rB1 * CG_LDA + gB1] = bpl1;
            // prefetch next segment's B
            if (!(c8 == 7 && t == 2)) {
                const int t2  = (t == 2) ? 0 : (t + 1);
                const int c82 = c8 + (t == 2);
                const int kbase = t2 * 256 + c82 * 32;
                const size_t gi0 = (size_t)(o0 + rB0) * 768 + kbase + gB0;
                const size_t gi1 = (size_t)(o0 + rB1) * 768 + kbase + gB1;
                bph0 = *(const uint4*)(wth + gi0); bpl0 = *(const uint4*)(wtl + gi0);
                bph1 = *(const uint4*)(wth + gi1); bpl1 = *(const uint4*)(wtl + gi1);
            }
            __syncthreads();   // tiles ready
            // MFMA segment (2-pass)
            short8 ah[2];
#pragma unroll
            for (int mt = 0; mt < 2; ++mt) {
                const int ar = (wave * 32 + mt * 16 + m16 + t) * CG_LDA + quad * 8;
                ah[mt] = *(const short8*)&As[ar];
            }
#pragma unroll
            for (int nt = 0; nt < 8; ++nt) {
                const int br = (nt * 16 + m16) * CG_LDA + quad * 8;
                const short8 bh = *(const short8*)&Bh[br];
                const short8 bl = *(const short8*)&Bl[br];
#pragma unroll
                for (int mt = 0; mt < 2; ++mt) {
                    acc[mt][nt] = __builtin_amdgcn_mfma_f32_16x16x32_bf16(ah[mt], bh, acc[mt][nt], 0, 0, 0);
                    acc[mt][nt] = __builtin_amdgcn_mfma_f32_16x16x32_bf16(ah[mt], bl, acc[mt][nt], 0, 0, 0);
                }
            }
        }
    }
    __syncthreads();

    // epilogue: +bias, *mask, store c[b][o][s] (float4 over s)
    float msk[2][4];
#pragma unroll
    for (int mt = 0; mt < 2; ++mt) {
        const int s = s0 + wave * 32 + mt * 16 + quad * 4;
        const int4 p4 = *(const int4*)(pos + (size_t)b * S_LEN + s);
        msk[mt][0] = (p4.x != -1) ? 1.f : 0.f;
        msk[mt][1] = (p4.y != -1) ? 1.f : 0.f;
        msk[mt][2] = (p4.z != -1) ? 1.f : 0.f;
        msk[mt][3] = (p4.w != -1) ? 1.f : 0.f;
    }
#pragma unroll
    for (int nt = 0; nt < 8; ++nt) {
        const int o = o0 + nt * 16 + m16;
        const float cb = convb[o];
#pragma unroll
        for (int mt = 0; mt < 2; ++mt) {
            const int s = s0 + wave * 32 + mt * 16 + quad * 4;
            float4 r;
            r.x = (acc[mt][nt][0] + cb) * msk[mt][0];
            r.y = (acc[mt][nt][1] + cb) * msk[mt][1];
            r.z = (acc[mt][nt][2] + cb) * msk[mt][2];
            r.w = (acc[mt][nt][3] + cb) * msk[mt][3];
            *(float4*)(c + ((size_t)(b * 768 + o)) * S_LEN + s) = r;
        }
    }
}

// ---------------- RoPE + FF (MFMA, LDS-staged B) + L1-normalize -> hh[b][i][d][s] ----------------
#define FF_LDA 264   // 256 + 8 ushort pad: rows 528B apart (33*16B, 2-way banks = free)
#define FF_LDB 136   // 128 + 8 pad: rows 272B apart (17*16B)
__global__ __launch_bounds__(256, 2) void k_ff(
    const float* __restrict__ emb, const int* __restrict__ pos, const float* __restrict__ minp,
    const unsigned short* __restrict__ w1th, const unsigned short* __restrict__ w1tl,
    const float* __restrict__ b1,
    const float* __restrict__ lng, const float* __restrict__ lnb,
    const unsigned short* __restrict__ w2th, const unsigned short* __restrict__ w2tl,
    const float* __restrict__ b2, const float* __restrict__ ffs, float* __restrict__ hh)
{
    const int b   = blockIdx.y;
    const int s0  = blockIdx.x * 64;
    const int tid = threadIdx.x;
    const int wave = tid >> 6, lane = tid & 63;
    const int m16  = lane & 15, quad = lane >> 4;

    __shared__ __align__(16) unsigned short Th[64 * FF_LDA];
    __shared__ __align__(16) unsigned short Tl[64 * FF_LDA];
    __shared__ __align__(16) unsigned short Bsh[16 * FF_LDB];
    __shared__ __align__(16) unsigned short Bsl[16 * FF_LDB];
    __shared__ float th_s[128];

    if (tid < 128) th_s[tid] = expf(-(float)tid * 0.07195578415606394f);
    __syncthreads();

    // ---- RoPE -> Th/Tl (each thread: 1/4 of one row = 64 cols = 32 pairs) ----
    {
        const int r    = tid >> 2;            // 0..63
        const int col0 = (tid & 3) * 64;
        const int s    = s0 + r;
        const int p    = pos[(size_t)b * S_LEN + s];
        const float adj = (p == -1) ? -1.f : ((float)p - minp[b]);
        const float* ep = emb + ((size_t)b * S_LEN + s) * D_DIM;
#pragma unroll
        for (int p8 = 0; p8 < 8; ++p8) {
            const int cbase = col0 + p8 * 8;
            const float4 va = *(const float4*)(ep + cbase);
            const float4 vb4 = *(const float4*)(ep + cbase + 4);
            const float x[8] = {va.x, va.y, va.z, va.w, vb4.x, vb4.y, vb4.z, vb4.w};
            unsigned int uh[4], ul[4];
#pragma unroll
            for (int jj = 0; jj < 4; ++jj) {
                const int j = (cbase >> 1) + jj;
                const float theta = th_s[j];
                float sn, cs;
                sincosf(adj * theta, &sn, &cs);
                const float x1 = x[2*jj], x2 = x[2*jj+1];
                const float r1 = x1 * cs - x2 * sn;
                const float r2 = x1 * sn + x2 * cs;
                const unsigned int h1 = f2bf(r1), h2 = f2bf(r2);
                uh[jj] = h1 | (h2 << 16);
                ul[jj] = f2bf(r1 - bf2f(h1)) | (f2bf(r2 - bf2f(h2)) << 16);
            }
            uint4 wh, wl;
            wh.x = uh[0]; wh.y = uh[1]; wh.z = uh[2]; wh.w = uh[3];
            wl.x = ul[0]; wl.y = ul[1]; wl.z = ul[2]; wl.w = ul[3];
            *(uint4*)&Th[r * FF_LDA + cbase] = wh;
            *(uint4*)&Tl[r * FF_LDA + cbase] = wl;
        }
    }
    __syncthreads();

    const int rowA  = wave * 16 + m16;
    const int strow = tid >> 4;           // staging: row 0..15
    const int stks  = (tid & 15) * 8;     // staging: k-segment

    // ---- GEMM1: H[64x256] = T @ W1 (3-pass split, LDS-staged B, reg-dbuf) ----
    f32x4 acc1[16];
#pragma unroll
    for (int nt = 0; nt < 16; ++nt)
#pragma unroll
        for (int e = 0; e < 4; ++e) acc1[nt][e] = 0.f;

    uint4 pfh, pfl;
    {
        const size_t gi = (size_t)strow * 256 + stks;   // nt=0, kh=0
        pfh = *(const uint4*)(w1th + gi);
        pfl = *(const uint4*)(w1tl + gi);
    }
    for (int kh = 0; kh < 2; ++kh) {
        short8 a1h[4], a1l[4];
#pragma unroll
        for (int c4 = 0; c4 < 4; ++c4) {
            const int ar = rowA * FF_LDA + kh * 128 + c4 * 32 + quad * 8;
            a1h[c4] = *(const short8*)&Th[ar];
            a1l[c4] = *(const short8*)&Tl[ar];
        }
#pragma unroll
        for (int nt = 0; nt < 16; ++nt) {
            __syncthreads();   // previous tile's consumers done
            *(uint4*)&Bsh[strow * FF_LDB + stks] = pfh;
            *(uint4*)&Bsl[strow * FF_LDB + stks] = pfl;
            if (!(kh == 1 && nt == 15)) {
                const int nt2 = (nt + 1) & 15;
                const int kh2 = kh + (nt == 15);
                const size_t gi = (size_t)(nt2 * 16 + strow) * 256 + kh2 * 128 + stks;
                pfh = *(const uint4*)(w1th + gi);
                pfl = *(const uint4*)(w1tl + gi);
            }
            __syncthreads();   // tile ready
#pragma unroll
            for (int c4 = 0; c4 < 4; ++c4) {
                const int br = m16 * FF_LDB + c4 * 32 + quad * 8;
                const short8 bh = *(const short8*)&Bsh[br];
                const short8 bl = *(const short8*)&Bsl[br];
                acc1[nt] = __builtin_amdgcn_mfma_f32_16x16x32_bf16(a1h[c4], bh, acc1[nt], 0, 0, 0);
                acc1[nt] = __builtin_amdgcn_mfma_f32_16x16x32_bf16(a1h[c4], bl, acc1[nt], 0, 0, 0);
                acc1[nt] = __builtin_amdgcn_mfma_f32_16x16x32_bf16(a1l[c4], bh, acc1[nt], 0, 0, 0);
            }
        }
    }

    // ---- +b1, LayerNorm stats (in-register, shfl over m16 group) ----
    float sume[4] = {0.f, 0.f, 0.f, 0.f}, sumq[4] = {0.f, 0.f, 0.f, 0.f};
#pragma unroll
    for (int nt = 0; nt < 16; ++nt) {
        const float bb = b1[nt * 16 + m16];
#pragma unroll
        for (int e = 0; e < 4; ++e) {
            const float v = acc1[nt][e] + bb;
            acc1[nt][e] = v;
            sume[e] += v;
            sumq[e] += v * v;
        }
    }
#pragma unroll
    for (int e = 0; e < 4; ++e) {
#pragma unroll
        for (int off = 1; off < 16; off <<= 1) {
            sume[e] += __shfl_xor(sume[e], off, 64);
            sumq[e] += __shfl_xor(sumq[e], off, 64);
        }
    }
    float mu[4], rs[4];
#pragma unroll
    for (int e = 0; e < 4; ++e) {
        mu[e] = sume[e] * (1.f / 256.f);
        const float var = sumq[e] * (1.f / 256.f) - mu[e] * mu[e];
        rs[e] = rsqrtf(var + 1e-5f);
    }

    // preload GEMM2 tile (0,0) while LN finishes
    {
        const size_t gi = (size_t)strow * 256 + stks;
        pfh = *(const uint4*)(w2th + gi);
        pfl = *(const uint4*)(w2tl + gi);
    }

    // ---- LN + GELU + split, write H back into Th/Tl ----
    __syncthreads();   // all waves done reading T / Bs
#pragma unroll
    for (int nt = 0; nt < 16; ++nt) {
        const int col = nt * 16 + m16;
        const float g  = lng[col];
        const float be = lnb[col];
#pragma unroll
        for (int e = 0; e < 4; ++e) {
            const float h  = (acc1[nt][e] - mu[e]) * rs[e] * g + be;
            const float hg = 0.5f * h * (1.f + erff(h * 0.7071067811865475f));
            const unsigned int hb = f2bf(hg);
            const int li = (wave * 16 + quad * 4 + e) * FF_LDA + col;
            Th[li] = (unsigned short)hb;
            Tl[li] = (unsigned short)f2bf(hg - bf2f(hb));
        }
    }
    __syncthreads();

    // ---- GEMM2: A[64x512] = Hg @ W2 (3-pass split, LDS-staged B, reg-dbuf) ----
    f32x4 acc2[32];
#pragma unroll
    for (int nt = 0; nt < 32; ++nt)
#pragma unroll
        for (int e = 0; e < 4; ++e) acc2[nt][e] = 0.f;

    for (int kh = 0; kh < 2; ++kh) {
        short8 a2h[4], a2l[4];
#pragma unroll
        for (int c4 = 0; c4 < 4; ++c4) {
            const int ar = rowA * FF_LDA + kh * 128 + c4 * 32 + quad * 8;
            a2h[c4] = *(const short8*)&Th[ar];
            a2l[c4] = *(const short8*)&Tl[ar];
        }
#pragma unroll
        for (int nt = 0; nt < 32; ++nt) {
            __syncthreads();
            *(uint4*)&Bsh[strow * FF_LDB + stks] = pfh;
            *(uint4*)&Bsl[strow * FF_LDB + stks] = pfl;
            if (!(kh == 1 && nt == 31)) {
                const int nt2 = (nt + 1) & 31;
                const int kh2 = kh + (nt == 31);
                const size_t gi = (size_t)(nt2 * 16 + strow) * 256 + kh2 * 128 + stks;
                pfh = *(const uint4*)(w2th + gi);
                pfl = *(const uint4*)(w2tl + gi);
            }
            __syncthreads();
#pragma unroll
            for (int c4 = 0; c4 < 4; ++c4) {
                const int br = m16 * FF_LDB + c4 * 32 + quad * 8;
                const short8 bh = *(const short8*)&Bsh[br];
                const short8 bl = *(const short8*)&Bsl[br];
                acc2[nt] = __builtin_amdgcn_mfma_f32_16x16x32_bf16(a2h[c4], bh, acc2[nt], 0, 0, 0);
                acc2[nt] = __builtin_amdgcn_mfma_f32_16x16x32_bf16(a2h[c4], bl, acc2[nt], 0, 0, 0);
                acc2[nt] = __builtin_amdgcn_mfma_f32_16x16x32_bf16(a2l[c4], bh, acc2[nt], 0, 0, 0);
            }
        }
    }

    // ---- (a+b2)*ffs, L1-norm per (row, half), store hh[b][i][d][s] ----
    float sm[2][4] = {{0.f,0.f,0.f,0.f},{0.f,0.f,0.f,0.f}};
#pragma unroll
    for (int nt = 0; nt < 32; ++nt) {
        const int col = nt * 16 + m16;
        const float bb = b2[col];
        const float fs = ffs[col];
#pragma unroll
        for (int e = 0; e < 4; ++e) {
            const float v = (acc2[nt][e] + bb) * fs;
            acc2[nt][e] = v;
            sm[nt >> 4][e] += fabsf(v);
        }
    }
#pragma unroll
    for (int i = 0; i < 2; ++i)
#pragma unroll
        for (int e = 0; e < 4; ++e) {
#pragma unroll
            for (int off = 1; off < 16; off <<= 1)
                sm[i][e] += __shfl_xor(sm[i][e], off, 64);
        }
#pragma unroll
    for (int nt = 0; nt < 32; ++nt) {
        const int i = nt >> 4;
        const int d = (nt & 15) * 16 + m16;
        float4 o4;
        o4.x = acc2[nt][0] / (sm[i][0] + 1e-8f);
        o4.y = acc2[nt][1] / (sm[i][1] + 1e-8f);
        o4.z = acc2[nt][2] / (sm[i][2] + 1e-8f);
        o4.w = acc2[nt][3] / (sm[i][3] + 1e-8f);
        *(float4*)(hh + ((size_t)((b * 2 + i) * 256 + d)) * S_LEN + s0 + wave * 16 + quad * 4) = o4;
    }
}

// ---------------- MFMA blocked-Toeplitz causal long conv (unchanged) ----------------
#define XS_PAD   960
#define XS_ELEMS 5056
#define FRX_WORDS 4160
__device__ __forceinline__ int xsw(int blk) { return blk ^ ((blk >> 3) & 7); }

__global__ __launch_bounds__(64) void k_conv_mfma(
    const float* __restrict__ xbuf, const int xC, const int xoff,
    const float* __restrict__ hh, const int iord,
    const float* __restrict__ cbuf, float* __restrict__ outb)
{
    const int d = blockIdx.x;
    const int b = blockIdx.y;
    const int lane = threadIdx.x;
    const float* xp = xbuf + ((size_t)(b * xC + xoff + d)) * S_LEN;
    const float* fp = hh   + ((size_t)((b * 2 + iord) * 256 + d)) * S_LEN;
    const float* zp = cbuf + ((size_t)(b * 768 + iord * 256 + d)) * S_LEN;
    float* op = outb + ((size_t)(b * 256 + d)) * S_LEN;

    __shared__ unsigned short xs[XS_ELEMS];
    __shared__ unsigned int   frx[FRX_WORDS];

    {
        for (int blk = lane; blk < 120; blk += 64) {
            int4 z; z.x = 0; z.y = 0; z.z = 0; z.w = 0;
            *(int4*)(xs + xsw(blk) * 8) = z;
        }
#pragma unroll
        for (int it = 0; it < 8; ++it) {
            const int idx = it * 64 + lane;
            const int j = idx * 8;
            const float4 v0 = *(const float4*)(xp + j);
            const float4 v1 = *(const float4*)(xp + j + 4);
            int4 w;
            w.x = (int)(f2bf(v0.x) | (f2bf(v0.y) << 16));
            w.y = (int)(f2bf(v0.z) | (f2bf(v0.w) << 16));
            w.z = (int)(f2bf(v1.x) | (f2bf(v1.y) << 16));
            w.w = (int)(f2bf(v1.z) | (f2bf(v1.w) << 16));
            *(int4*)(xs + xsw(120 + idx) * 8) = w;
        }
    }
    {
        frx[4096 + lane] = 0u;
        if (lane == 0) frx[4095] = f2bf(fp[0]);
#pragma unroll
        for (int it = 0; it < 16; ++it) {
            const int j = (it * 64 + lane) * 4;
            const float4 v = *(const float4*)(fp + j);
            const float f4 = (j + 4 < S_LEN) ? fp[j + 4] : 0.f;
            frx[4094 - j] = f2bf(v.y) | (f2bf(v.x) << 16);
            frx[4093 - j] = f2bf(v.z) | (f2bf(v.y) << 16);
            frx[4092 - j] = f2bf(v.w) | (f2bf(v.z) << 16);
            if (j < 4092) frx[4091 - j] = f2bf(f4) | (f2bf(v.w) << 16);
        }
    }
    __syncthreads();

    const int m    = lane & 15;
    const int quad = lane >> 4;

    f32x4 acc[4][4];
#pragma unroll
    for (int mt = 0; mt < 4; ++mt)
#pragma unroll
        for (int pt = 0; pt < 4; ++pt)
#pragma unroll
            for (int e = 0; e < 4; ++e) acc[mt][pt][e] = 0.f;

    const int eA_base = 4095 - m + quad * 8;
    const int oB_base = XS_PAD + 64 * m + quad * 8;

    for (int r = 0; r < 64; ++r) {
        const int ea_r = eA_base - 64 * r;
        short8 afr[4][2];
#pragma unroll
        for (int mt = 0; mt < 4; ++mt)
#pragma unroll
            for (int kc = 0; kc < 2; ++kc) {
                const int e = ea_r - 16 * mt + 32 * kc;
                union { unsigned int u[4]; short8 s; } cvt;
                cvt.u[0] = frx[e];
                cvt.u[1] = frx[e + 2];
                cvt.u[2] = frx[e + 4];
                cvt.u[3] = frx[e + 6];
                afr[mt][kc] = cvt.s;
            }
        const int ptmin = r >> 4;
        const int ob_r = oB_base - 64 * r;
#pragma unroll
        for (int pt = 0; pt < 4; ++pt) {
            if (pt >= ptmin) {
                const int o0 = ob_r + 1024 * pt;
                const short8 bfr0 = *(const short8*)(xs + xsw(o0 >> 3) * 8);
                const short8 bfr1 = *(const short8*)(xs + xsw((o0 + 32) >> 3) * 8);
#pragma unroll
                for (int mt = 0; mt < 4; ++mt) {
                    acc[mt][pt] = __builtin_amdgcn_mfma_f32_16x16x32_bf16(afr[mt][0], bfr0, acc[mt][pt], 0, 0, 0);
                    acc[mt][pt] = __builtin_amdgcn_mfma_f32_16x16x32_bf16(afr[mt][1], bfr1, acc[mt][pt], 0, 0, 0);
                }
            }
        }
    }

    const float inv = 1.f / 8192.f;
#pragma unroll
    for (int mt = 0; mt < 4; ++mt)
#pragma unroll
        for (int pt = 0; pt < 4; ++pt) {
            const int p  = 16 * pt + m;
            const int s0 = 64 * p + 16 * mt + quad * 4;
            const float4 z4 = *(const float4*)(zp + s0);
            float4 o4;
            o4.x = z4.x * acc[mt][pt][0] * inv;
            o4.y = z4.y * acc[mt][pt][1] * inv;
            o4.z = z4.z * acc[mt][pt][2] * inv;
            o4.w = z4.w * acc[mt][pt][3] * inv;
            *(float4*)(op + s0) = o4;
        }
}

// ---------------- out[b][s][e] = mask * (sum_d v[b][d][s] * W_out[d][e] + b_out[e]) ----------------
__global__ __launch_bounds__(256) void k_out(
    const float* __restrict__ v, const float* __restrict__ Wo,
    const float* __restrict__ bo, const int* __restrict__ pos,
    float* __restrict__ out)
{
    const int b   = blockIdx.y;
    const int s0  = blockIdx.x * 32;
    const int tid = threadIdx.x;
    __shared__ float vs[256 * 36];
    {
        const float4* src = (const float4*)(v + ((size_t)(b*256 + tid)) * S_LEN + s0);
#pragma unroll
        for (int q = 0; q < 8; ++q) {
            *(float4*)&vs[tid*36 + q*4] = src[q];
        }
    }
    __syncthreads();
    float acc[32];
#pragma unroll
    for (int r = 0; r < 32; ++r) acc[r] = 0.f;
    for (int dd = 0; dd < 256; ++dd) {
        const float w = Wo[(size_t)dd * 256 + tid];
        const float* vr = &vs[dd * 36];
#pragma unroll
        for (int q = 0; q < 8; ++q) {
            const float4 x4 = *(const float4*)&vr[q*4];
            acc[q*4+0] += x4.x * w;
            acc[q*4+1] += x4.y * w;
            acc[q*4+2] += x4.z * w;
            acc[q*4+3] += x4.w * w;
        }
    }
    const float bb = bo[tid];
#pragma unroll
    for (int r = 0; r < 32; ++r) {
        const int s = s0 + r;
        const float m = (pos[(size_t)b * S_LEN + s] != -1) ? 1.f : 0.f;
        out[((size_t)b * S_LEN + s) * 256 + tid] = (acc[r] + bb) * m;
    }
}

extern "C" void kernel_launch(void* const* d_in, const int* in_sizes, int n_in,
                              void* d_out, int out_size, void* d_ws, size_t ws_size,
                              hipStream_t stream) {
    const float* emb = (const float*)d_in[0];
    const int*   pos = (const int*)  d_in[1];
    const float* Wp  = (const float*)d_in[2];
    const float* cw  = (const float*)d_in[3];
    const float* cb  = (const float*)d_in[4];
    const float* W1  = (const float*)d_in[5];
    const float* b1  = (const float*)d_in[6];
    const float* lg  = (const float*)d_in[7];
    const float* lb  = (const float*)d_in[8];
    const float* W2  = (const float*)d_in[9];
    const float* b2  = (const float*)d_in[10];
    const float* ffs = (const float*)d_in[11];
    const float* Wo  = (const float*)d_in[12];
    const float* bo  = (const float*)d_in[13];

    float* ws   = (float*)d_ws;
    float* minp = ws + OFF_MINP;
    float* wpt  = ws + OFF_WPT;
    unsigned short* wth = (unsigned short*)(ws + OFF_WTH);
    unsigned short* wtl = (unsigned short*)(ws + OFF_WTL);
    float* c    = ws + OFF_C;
    float* hh   = ws + OFF_HH;
    float* vb   = ws + OFF_V;
    float* ub   = ws + OFF_U;

    // FF weight splits carved from the head of vb (consumed by k_ff before conv#1 writes vb)
    unsigned short* w1th = (unsigned short*)vb;
    unsigned short* w1tl = w1th + 256 * 256;
    unsigned short* w2th = w1tl + 256 * 256;
    unsigned short* w2tl = w2th + 512 * 256;

    k_minpos<<<dim3(8), dim3(256), 0, stream>>>(pos, minp);
    k_wpt<<<dim3(24, 8), dim3(256), 0, stream>>>(Wp, wpt);
    k_weff<<<dim3(768), dim3(256), 0, stream>>>(wpt, cw, wth, wtl);
    k_tsplit<<<dim3(8, 8), dim3(256), 0, stream>>>(W1, 256, 256, w1th, w1tl);
    k_tsplit<<<dim3(16, 8), dim3(256), 0, stream>>>(W2, 256, 512, w2th, w2tl);
    k_convgemm<<<dim3(32, 6, 8), dim3(256), 0, stream>>>(emb, pos, wth, wtl, cb, c);
    k_ff<<<dim3(64, 8), dim3(256), 0, stream>>>(emb, pos, minp, w1th, w1tl, b1, lg, lb, w2th, w2tl, b2, ffs, hh);
    // v = zs[2]; v = zs[0] * longconv(v, hh[:,0]); v = zs[1] * longconv(v, hh[:,1])
    k_conv_mfma<<<dim3(256, 8), dim3(64), 0, stream>>>(c, 768, 512, hh, 0, c, vb);
    k_conv_mfma<<<dim3(256, 8), dim3(64), 0, stream>>>(vb, 256, 0, hh, 1, c, ub);
    k_out<<<dim3(128, 8), dim3(256), 0, stream>>>(ub, Wo, bo, pos, (float*)d_out);
}